// Round 1
// 579.344 us; speedup vs baseline: 1.6590x; 1.6590x over previous
//
#include <hip/hip_runtime.h>

typedef unsigned long long u64;
#define THRESH 0.5f
#define ALL1 0xFFFFFFFFFFFFFFFFull
#define FINF __builtin_inff()

__device__ __forceinline__ u64 shflxU64(u64 v, int m) { return __shfl_xor(v, m, 64); }
__device__ __forceinline__ int waveMaxI(int v) {
#pragma unroll
    for (int off = 1; off < 64; off <<= 1) {
        int o = __shfl_xor(v, off, 64);
        v = v > o ? v : o;
    }
    return v;
}
// Full bitonic sort of 64 u64 keys (one per lane), ascending across lanes.
__device__ __forceinline__ void sort64(u64 &key, int lane) {
#pragma unroll
    for (int k = 2; k <= 64; k <<= 1) {
#pragma unroll
        for (int j = k >> 1; j > 0; j >>= 1) {
            u64 p = shflxU64(key, j);
            bool takeMax = ((lane & j) != 0) != ((lane & k) != 0);
            u64 mn = key < p ? key : p;
            u64 mx = key < p ? p : key;
            key = takeMax ? mx : mn;
        }
    }
}

// ---------------- K1: valid scan, appends, candidate compaction ----------------
__global__ __launch_bounds__(1024) void k1_scan(
    const float* __restrict__ scores, const float* __restrict__ priorities,
    const int* __restrict__ countPtr, int N, int P,
    float* __restrict__ outPrior, float* __restrict__ outCnt, int* __restrict__ srcWs,
    float* __restrict__ cval, int* __restrict__ csrc, int* __restrict__ meta)
{
    const int tid = threadIdx.x;
    for (int s = tid; s < P; s += 1024) { outPrior[s] = priorities[s]; srcWs[s] = -1; }
    int C0 = *countPtr; C0 = C0 < 0 ? 0 : (C0 > P ? P : C0);
    const int per = (N + 1023) >> 10;
    const int i0 = tid * per;
    const int i1 = min(i0 + per, N);
    int c = 0;
    for (int i = i0; i < i1; ++i) c += (scores[i] > THRESH) ? 1 : 0;
    __shared__ int sb[1024];
    sb[tid] = c; __syncthreads();
    for (int off = 1; off < 1024; off <<= 1) {
        int v = (tid >= off) ? sb[tid - off] : 0;
        __syncthreads();
        sb[tid] += v;
        __syncthreads();
    }
    const int total = sb[1023];
    int v = sb[tid] - c;  // exclusive prefix of valid count
    int A = P - C0; if (A > total) A = total; if (A < 0) A = 0;
    for (int i = i0; i < i1; ++i) {
        float sc = scores[i];
        if (sc > THRESH) {
            if (v < A) { outPrior[C0 + v] = sc; srcWs[C0 + v] = i; }
            else { cval[v - A] = sc; csrc[v - A] = i; }
            ++v;
        }
    }
    if (tid == 0) {
        meta[0] = total - A;      // M: number of replacement candidates
        meta[1] = C0 + A;         // F: filled pool size after appends
        outCnt[0] = (float)(C0 + A);
    }
}

// ---------------- K2: success flags via dominance count ----------------
// cand i succeeds iff #{V < c_i} + #{j<i : c_j < c_i} >= i+1
__global__ __launch_bounds__(256) void k2_succ(
    const float* __restrict__ outPrior, const float* __restrict__ cval,
    const int* __restrict__ meta, int* __restrict__ succ)
{
    const int M = meta[0], F = meta[1];
    if (blockIdx.x * 256 >= M) return;
    const int i = blockIdx.x * 256 + threadIdx.x;
    __shared__ __align__(16) float tile[4096];
    const bool live = i < M;
    const float x = live ? cval[i] : 0.f;
    int cnt = 0;
    for (int tb = 0; tb < F; tb += 4096) {
        const int te = min(F - tb, 4096);
        for (int t = threadIdx.x; t < 4096; t += 256)
            tile[t] = (t < te) ? outPrior[tb + t] : FINF;
        __syncthreads();
        if (live) {
            const float4* t4 = (const float4*)tile;
            const int n4 = (te + 3) >> 2;
            for (int t = 0; t < n4; ++t) {
                float4 w = t4[t];
                cnt += (w.x < x) + (w.y < x) + (w.z < x) + (w.w < x);
            }
        }
        __syncthreads();
    }
    const int maxI = min(M, (int)(blockIdx.x * 256 + 256));
    for (int tb = 0; tb < maxI; tb += 4096) {
        const int te = min(M - tb, 4096);
        for (int t = threadIdx.x; t < 4096; t += 256)
            tile[t] = (t < te) ? cval[tb + t] : FINF;
        __syncthreads();
        if (live) {
            int lim = i - tb; if (lim > te) lim = te;
            if (lim > 0) {
                const int l4 = lim >> 2;
                const float4* t4 = (const float4*)tile;
                for (int t = 0; t < l4; ++t) {
                    float4 w = t4[t];
                    cnt += (w.x < x) + (w.y < x) + (w.z < x) + (w.w < x);
                }
                for (int t = l4 << 2; t < lim; ++t) cnt += tile[t] < x;
            }
        }
        __syncthreads();
    }
    if (live) succ[i] = (cnt >= i + 1) ? 1 : 0;
}

// ---------------- K3: scan succ -> write numbers, compact writes ----------------
__global__ __launch_bounds__(1024) void k3_compact(
    const float* __restrict__ cval, const int* __restrict__ csrc,
    const int* __restrict__ succ, int* __restrict__ meta,
    float* __restrict__ cvalS, float* __restrict__ wval, int* __restrict__ wsrc,
    int* __restrict__ writeNum)
{
    const int M = meta[0];
    const int tid = threadIdx.x;
    const int per = (M + 1023) >> 10;
    const int i0 = tid * per, i1 = min(i0 + per, M);
    int c = 0;
    for (int i = i0; i < i1; ++i) c += succ[i];
    __shared__ int sb[1024];
    sb[tid] = c; __syncthreads();
    for (int off = 1; off < 1024; off <<= 1) {
        int v = (tid >= off) ? sb[tid - off] : 0;
        __syncthreads();
        sb[tid] += v;
        __syncthreads();
    }
    int w = sb[tid] - c;
    for (int i = i0; i < i1; ++i) {
        if (succ[i]) {
            wval[w] = cval[i]; wsrc[w] = csrc[i]; writeNum[i] = w; cvalS[i] = cval[i]; ++w;
        } else { writeNum[i] = -1; cvalS[i] = FINF; }
    }
    if (tid == 0) meta[2] = sb[1023];   // R: number of successful writes
}

// ---------------- K4: ranks in W = V ∪ C_succ, scatter evicted list ----------------
__global__ __launch_bounds__(256) void k4_rank(
    const float* __restrict__ outPrior, const float* __restrict__ cvalS,
    const int* __restrict__ writeNum, const int* __restrict__ meta, int P,
    float* __restrict__ evV, int* __restrict__ evId, int* __restrict__ survW)
{
    const int M = meta[0], F = meta[1], R = meta[2];
    if (M == 0) return;
    const int tot = F + M;
    if (blockIdx.x * 256 >= tot) return;
    const int e = blockIdx.x * 256 + threadIdx.x;
    float x = 0.f; int myid = 0; bool isCand = false; int wn = -1;
    bool live = e < tot;
    if (live) {
        if (e < F) { x = outPrior[e]; myid = e; }
        else {
            const int i = e - F;
            x = cvalS[i]; myid = P + i; isCand = true;
            if (x == FINF) live = false; else wn = writeNum[i];
        }
    }
    int cnt = 0;
    __shared__ __align__(16) float tile[2048];
    for (int tb = 0; tb < F; tb += 2048) {
        const int te = min(F - tb, 2048);
        for (int t = threadIdx.x; t < 2048; t += 256)
            tile[t] = (t < te) ? outPrior[tb + t] : FINF;
        __syncthreads();
        if (live) {
            const float4* t4 = (const float4*)tile;
            const int n4 = (te + 3) >> 2;
            for (int q = 0; q < n4; ++q) {
                const float4 w = t4[q];
                const int idb = tb + (q << 2);
                cnt += (int)((w.x < x) | ((w.x == x) & (idb < myid)));
                cnt += (int)((w.y < x) | ((w.y == x) & (idb + 1 < myid)));
                cnt += (int)((w.z < x) | ((w.z == x) & (idb + 2 < myid)));
                cnt += (int)((w.w < x) | ((w.w == x) & (idb + 3 < myid)));
            }
        }
        __syncthreads();
    }
    for (int tb = 0; tb < M; tb += 2048) {
        const int te = min(M - tb, 2048);
        for (int t = threadIdx.x; t < 2048; t += 256)
            tile[t] = (t < te) ? cvalS[tb + t] : FINF;
        __syncthreads();
        if (live) {
            const float4* t4 = (const float4*)tile;
            const int n4 = (te + 3) >> 2;
            for (int q = 0; q < n4; ++q) {
                const float4 w = t4[q];
                const int idb = P + tb + (q << 2);
                cnt += (int)((w.x < x) | ((w.x == x) & (idb < myid)));
                cnt += (int)((w.y < x) | ((w.y == x) & (idb + 1 < myid)));
                cnt += (int)((w.z < x) | ((w.z == x) & (idb + 2 < myid)));
                cnt += (int)((w.w < x) | ((w.w == x) & (idb + 3 < myid)));
            }
        }
        __syncthreads();
    }
    if (live) {
        if (isCand) survW[wn] = (cnt >= R) ? 1 : 0;
        if (cnt < R + 64) { evV[cnt] = x; evId[cnt] = isCand ? (P + wn) : myid; }
    }
}

// ---------------- K5: chunked slot-chain resolution (exact tie handling) ----------------
#define SCAP 14400
__global__ __launch_bounds__(64, 1) void k5_chain(
    const float* __restrict__ evV, const int* __restrict__ evId,
    const int* __restrict__ meta, int P,
    int* __restrict__ Sg, int* __restrict__ survW)
{
    __shared__ int S[SCAP];
    const int lane = threadIdx.x;
    const int R = meta[2];
    if (R <= 0 || R > SCAP) return;
    const int F = meta[1];
    const int Wtot = F + R;

    // Rp: start of the equal-value run straddling the evicted/survivor boundary
    int Rp = R;
    {
        const float vR1 = evV[R - 1];
        const bool tieAtR = (R < Wtot) && (evV[R] == vR1);
        if (tieAtR) {
            const int rr = R - 1 - lane;
            const float v = (rr >= 0) ? evV[rr] : FINF;
            const u64 neq = __ballot(v != vR1);
            const int l = neq ? (__ffsll((long long)neq) - 1) : 64;
            Rp = R - l;
            if (Rp < 0) Rp = 0;
        }
    }

    // main loop over fully-evicted ranks [0, Rp), 64-ish at a time, cut at run starts
    int b = 0;
    while (b < Rp) {
        const int t = lane;
        const int r = b + t;
        const bool inW = r < Rp;
        const float val = inW ? evV[r] : FINF;
        const int id = inW ? evId[r] : 0;
        const float pv = __shfl_up(val, 1, 64);
        const bool tp = (t > 0) && inW && (val == pv);   // tied with previous rank
        const u64 starts = __ballot((!tp) && inW);
        int L;
        if (b + 64 >= Rp) L = Rp - b;
        else {
            const u64 m2 = starts & ~1ull;
            L = m2 ? (63 - __clzll((long long)m2)) : 64;  // cut at last run start
        }
        const bool active = t < L;
        const u64 activeMask = (L >= 64) ? ALL1 : ((1ull << L) - 1ull);
        const u64 sm = starts & activeMask;
        const u64 below = (2ull << t) - 1ull;             // bits 0..t (t=63 wraps to ALL1)
        const int rs = 63 - __clzll((long long)((sm & below) | 1ull));
        const u64 nxt = sm & ~below;
        const int re = nxt ? (__ffsll((long long)nxt) - 1) : L;
        const int runLen = re - rs;
        const u64 runMask = ((runLen >= 64) ? ALL1 : ((1ull << runLen) - 1ull)) << rs;

        const bool isInit = id < P;
        const int wn = id - P;                            // parent write index (if write)
        int ms = -1;                                      // member's current slot
        if (active) {
            if (isInit) ms = id;
            else if (wn < b) ms = S[wn];
        }
        int Sv = -1;                                      // assigned slot for this rank
        for (int iter = 0; iter < 80; ++iter) {
            const u64 asg = __ballot(Sv >= 0);
            if ((asg & activeMask) == activeMask) break;
            const int pl = wn - b;
            const int pS = __shfl(Sv, pl & 63, 64);
            if (active && ms < 0 && pl >= 0 && pl < 64 && ((asg >> pl) & 1ull)) ms = pS;
            const u64 msk = __ballot(ms >= 0);
            const bool ready = active && (Sv < 0) && ((msk & runMask) == runMask);
            const int maxRL = waveMaxI(ready ? runLen : 1);
            for (int ss = 0; ss < maxRL; ++ss) {          // odd-even sort run by slot
                const int po = (((t - rs) & 1) == (ss & 1)) ? (t + 1) : (t - 1);
                const int om = __shfl(ms, po & 63, 64);
                if (ready && runLen > 1 && po >= rs && po < re) {
                    ms = (po > t) ? (ms < om ? ms : om) : (ms > om ? ms : om);
                }
            }
            if (ready) Sv = ms;
        }
        if (active) { S[r] = Sv; Sg[r] = Sv; }
        b += L;
    }

    // boundary run [Rp, R): e evictions take the e smallest current slots
    if (Rp < R) {
        const int r = Rp + lane;
        const float v0 = evV[Rp];
        const bool mem = (r < Wtot) && (evV[r] == v0);
        const int g = (int)__popcll(__ballot(mem));
        const int e = R - Rp;
        int id = 0, ms = 0;
        if (mem) {
            id = evId[r];
            ms = (id < P) ? id : S[id - P];
        }
        u64 key = mem ? ((((u64)(unsigned)ms) << 32) | (u64)(unsigned)id) : ALL1;
        sort64(key, lane);
        const int sid = (int)(unsigned)(key & 0xFFFFFFFFull);
        const int sms = (int)(unsigned)(key >> 32);
        const bool real = (key != ALL1) && (lane < g);
        if (real && lane < e) { S[Rp + lane] = sms; Sg[Rp + lane] = sms; }
        if (real && sid >= P) survW[sid - P] = (lane >= e) ? 1 : 0;
    }
}

// ---------------- K5b: apply surviving writes ----------------
__global__ __launch_bounds__(256) void k5b_apply(
    const int* __restrict__ Sg, const int* __restrict__ survW,
    const float* __restrict__ wval, const int* __restrict__ wsrc,
    const int* __restrict__ meta,
    float* __restrict__ outPrior, int* __restrict__ srcWs)
{
    const int R = meta[2];
    const int j = blockIdx.x * 256 + threadIdx.x;
    if (j >= R) return;
    if (survW[j]) {
        const int s = Sg[j];
        outPrior[s] = wval[j];
        srcWs[s] = wsrc[j];
    }
}

// ---------------- gather: one block per pool row ----------------
__global__ __launch_bounds__(256) void gather_kernel(
    const float* __restrict__ summaries,
    const float* __restrict__ pool,
    const int* __restrict__ src,
    float* __restrict__ outPool, int D) {
    int p = blockIdx.x;
    int s = src[p];
    const float* row = (s >= 0) ? (summaries + (size_t)s * D) : (pool + (size_t)p * D);
    float* o = outPool + (size_t)p * D;
    if ((D & 3) == 0) {
        for (int k = (threadIdx.x << 2); k < D; k += (blockDim.x << 2)) {
            float4 v = *(const float4*)(row + k);
            *(float4*)(o + k) = v;
        }
    } else {
        for (int k = threadIdx.x; k < D; k += blockDim.x) o[k] = row[k];
    }
}

extern "C" void kernel_launch(void* const* d_in, const int* in_sizes, int n_in,
                              void* d_out, int out_size, void* d_ws, size_t ws_size,
                              hipStream_t stream) {
    const float* summaries  = (const float*)d_in[0];
    const float* scores     = (const float*)d_in[1];
    const float* pool       = (const float*)d_in[2];
    const float* priorities = (const float*)d_in[3];
    const int*   count      = (const int*)d_in[4];

    int N = in_sizes[1];            // 16384
    int P = in_sizes[3];            // 4096
    int D = in_sizes[0] / N;        // 1024

    float* outPool  = (float*)d_out;
    float* outPrior = outPool + (size_t)P * D;
    float* outCnt   = outPrior + P;
    int*   srcWs    = (int*)d_ws;   // P ints; must survive into gather

    // scratch lives inside outPool: gather fully overwrites it at the end
    float* cval     = outPool;
    int*   csrc     = (int*)outPool + 1 * N;
    int*   succ     = (int*)outPool + 2 * N;
    float* cvalS    = outPool + 3 * N;
    float* wval     = outPool + 4 * N;
    int*   wsrc     = (int*)outPool + 5 * N;
    int*   writeNum = (int*)outPool + 6 * N;
    float* evV      = outPool + 7 * N;                 // N + 64
    int*   evId     = (int*)outPool + 8 * N + 64;      // N + 64
    int*   Sgbuf    = (int*)outPool + 9 * N + 128;     // N
    int*   survW    = (int*)outPool + 10 * N + 128;    // N
    int*   meta     = (int*)outPool + 11 * N + 128;    // 8

    const int nb2 = (N + 255) / 256;
    const int nb4 = (P + N + 255) / 256;

    k1_scan<<<1, 1024, 0, stream>>>(scores, priorities, count, N, P,
                                    outPrior, outCnt, srcWs, cval, csrc, meta);
    k2_succ<<<nb2, 256, 0, stream>>>(outPrior, cval, meta, succ);
    k3_compact<<<1, 1024, 0, stream>>>(cval, csrc, succ, meta, cvalS, wval, wsrc, writeNum);
    k4_rank<<<nb4, 256, 0, stream>>>(outPrior, cvalS, writeNum, meta, P, evV, evId, survW);
    k5_chain<<<1, 64, 0, stream>>>(evV, evId, meta, P, Sgbuf, survW);
    k5b_apply<<<nb2, 256, 0, stream>>>(Sgbuf, survW, wval, wsrc, meta, outPrior, srcWs);
    gather_kernel<<<P, 256, 0, stream>>>(summaries, pool, srcWs, outPool, D);
}

// Round 2
// 280.324 us; speedup vs baseline: 3.4287x; 2.0667x over previous
//
#include <hip/hip_runtime.h>

typedef unsigned long long u64;
#define THRESH 0.5f
#define ALL1 0xFFFFFFFFFFFFFFFFull
#define FINF __builtin_inff()

__device__ __forceinline__ u64 shflxU64(u64 v, int m) { return __shfl_xor(v, m, 64); }
__device__ __forceinline__ int waveMaxI(int v) {
#pragma unroll
    for (int off = 1; off < 64; off <<= 1) {
        int o = __shfl_xor(v, off, 64);
        v = v > o ? v : o;
    }
    return v;
}
// Full bitonic sort of 64 u64 keys (one per lane), ascending across lanes.
__device__ __forceinline__ void sort64(u64 &key, int lane) {
#pragma unroll
    for (int k = 2; k <= 64; k <<= 1) {
#pragma unroll
        for (int j = k >> 1; j > 0; j >>= 1) {
            u64 p = shflxU64(key, j);
            bool takeMax = ((lane & j) != 0) != ((lane & k) != 0);
            u64 mn = key < p ? key : p;
            u64 mx = key < p ? p : key;
            key = takeMax ? mx : mn;
        }
    }
}

// ---------------- K1: valid scan, appends, candidate compaction, cnt zeroing ----------------
__global__ __launch_bounds__(1024) void k1_scan(
    const float* __restrict__ scores, const float* __restrict__ priorities,
    const int* __restrict__ countPtr, int N, int P,
    float* __restrict__ outPrior, float* __restrict__ outCnt, int* __restrict__ srcWs,
    float* __restrict__ cval, int* __restrict__ csrc, int* __restrict__ meta,
    int* __restrict__ cnt2, int* __restrict__ cnt4)
{
    const int tid = threadIdx.x;
    for (int s = tid; s < P; s += 1024) { outPrior[s] = priorities[s]; srcWs[s] = -1; }
    for (int s = tid; s < N; s += 1024) cnt2[s] = 0;
    for (int s = tid; s < P + N; s += 1024) cnt4[s] = 0;
    int C0 = *countPtr; C0 = C0 < 0 ? 0 : (C0 > P ? P : C0);
    const int per = (N + 1023) >> 10;
    const int i0 = tid * per;
    const int i1 = min(i0 + per, N);
    int c = 0;
    for (int i = i0; i < i1; ++i) c += (scores[i] > THRESH) ? 1 : 0;
    __shared__ int sb[1024];
    sb[tid] = c; __syncthreads();
    for (int off = 1; off < 1024; off <<= 1) {
        int v = (tid >= off) ? sb[tid - off] : 0;
        __syncthreads();
        sb[tid] += v;
        __syncthreads();
    }
    const int total = sb[1023];
    int v = sb[tid] - c;  // exclusive prefix of valid count
    int A = P - C0; if (A > total) A = total; if (A < 0) A = 0;
    for (int i = i0; i < i1; ++i) {
        float sc = scores[i];
        if (sc > THRESH) {
            if (v < A) { outPrior[C0 + v] = sc; srcWs[C0 + v] = i; }
            else { cval[v - A] = sc; csrc[v - A] = i; }
            ++v;
        }
    }
    if (tid == 0) {
        meta[0] = total - A;      // M: number of replacement candidates
        meta[1] = C0 + A;         // F: filled pool size after appends
        outCnt[0] = (float)(C0 + A);
    }
}

// ---------------- K2: split dominance count for success condition ----------------
// cnt2[i] = #{V < c_i} + #{j<i : c_j < c_i}; cand i succeeds iff cnt2[i] >= i+1.
// Unified source space s in [0, F+M): s<F -> pool value, else candidate j=s-F
// (element i may count sources s < F+i; per-thread lim handles the prefix).
#define K2T 1024
__global__ __launch_bounds__(256) void k2_count(
    const float* __restrict__ outPrior, const float* __restrict__ cval,
    const int* __restrict__ meta, int* __restrict__ cnt2)
{
    const int M = meta[0], F = meta[1];
    const int iB = blockIdx.x << 8;
    if (iB >= M) return;
    const int hi = min(M, iB + 256);
    const int totSrc = F + hi;            // sources possibly needed by this block
    const int tb = blockIdx.y * K2T;
    if (tb >= totSrc) return;
    const int te = min(totSrc - tb, K2T);
    const int i = iB + threadIdx.x;
    const bool live = i < M;
    const float x = live ? cval[i] : 0.f;
    __shared__ __align__(16) float tile[K2T];
    for (int t = threadIdx.x; t < K2T; t += 256) {
        const int s = tb + t;
        tile[t] = (t < te) ? ((s < F) ? outPrior[s] : cval[s - F]) : FINF;
    }
    __syncthreads();
    if (!live) return;
    int lim = F + i - tb;
    if (lim < 0) lim = 0;
    if (lim > te) lim = te;
    int cnt = 0;
    const int l4 = lim >> 2;
    const float4* t4 = (const float4*)tile;
    for (int q = 0; q < l4; ++q) {
        const float4 w = t4[q];
        cnt += (w.x < x) + (w.y < x) + (w.z < x) + (w.w < x);
    }
    for (int t = l4 << 2; t < lim; ++t) cnt += tile[t] < x;
    if (cnt) atomicAdd(&cnt2[i], cnt);
}

// ---------------- K3: succ from cnt2, scan -> write numbers, compact writes ----------------
__global__ __launch_bounds__(1024) void k3_compact(
    const float* __restrict__ cval, const int* __restrict__ csrc,
    const int* __restrict__ cnt2, int* __restrict__ meta,
    float* __restrict__ cvalS, float* __restrict__ wval, int* __restrict__ wsrc,
    int* __restrict__ writeNum)
{
    const int M = meta[0];
    const int tid = threadIdx.x;
    const int per = (M + 1023) >> 10;
    const int i0 = tid * per, i1 = min(i0 + per, M);
    int c = 0;
    for (int i = i0; i < i1; ++i) c += (cnt2[i] >= i + 1) ? 1 : 0;
    __shared__ int sb[1024];
    sb[tid] = c; __syncthreads();
    for (int off = 1; off < 1024; off <<= 1) {
        int v = (tid >= off) ? sb[tid - off] : 0;
        __syncthreads();
        sb[tid] += v;
        __syncthreads();
    }
    int w = sb[tid] - c;
    for (int i = i0; i < i1; ++i) {
        if (cnt2[i] >= i + 1) {
            wval[w] = cval[i]; wsrc[w] = csrc[i]; writeNum[i] = w; cvalS[i] = cval[i]; ++w;
        } else { writeNum[i] = -1; cvalS[i] = FINF; }
    }
    if (tid == 0) meta[2] = sb[1023];   // R: number of successful writes
}

// ---------------- K4a: split rank count in W = V ∪ C_succ, (value,id) keys ----------------
// id of source s: s<F ? s : P + (s-F). Tiles split at the F boundary so the id
// map is affine (offset 0 or P-F) within each counted segment.
#define K4T 1024
__global__ __launch_bounds__(256) void k4_count(
    const float* __restrict__ outPrior, const float* __restrict__ cvalS,
    const int* __restrict__ meta, int P, int* __restrict__ cnt4)
{
    const int M = meta[0], F = meta[1];
    if (M == 0) return;
    const int tot = F + M;
    const int eB = blockIdx.x << 8;
    if (eB >= tot) return;
    const int tb = blockIdx.y * K4T;
    if (tb >= tot) return;
    const int te = min(tot - tb, K4T);
    const int e = eB + threadIdx.x;
    bool live = e < tot;
    float x = 0.f; int myid = 0;
    if (live) {
        if (e < F) { x = outPrior[e]; myid = e; }
        else {
            x = cvalS[e - F]; myid = P + (e - F);
            if (x == FINF) live = false;
        }
    }
    __shared__ __align__(16) float tile[K4T];
    for (int t = threadIdx.x; t < K4T; t += 256) {
        const int s = tb + t;
        tile[t] = (t < te) ? ((s < F) ? outPrior[s] : cvalS[s - F]) : FINF;
    }
    __syncthreads();
    if (!live) return;
    int cnt = 0;
    int lim1 = F - tb;                   // tile-local boundary pool|candidates
    if (lim1 < 0) lim1 = 0;
    if (lim1 > te) lim1 = te;
    // segment [a,b) with id offset d: sid = tb + t + d
#define K4_SEG(a, b, d)                                                        \
    {                                                                          \
        const int a_ = (a), b_ = (b), d_ = (d);                                \
        int aa = (a_ + 3) & ~3; if (aa > b_) aa = b_;                          \
        for (int t = a_; t < aa; ++t) {                                        \
            const float v = tile[t]; const int sid = tb + t + d_;              \
            cnt += (int)((v < x) | ((v == x) & (sid < myid)));                 \
        }                                                                      \
        const int b4 = aa + (((b_ - aa) >> 2) << 2);                           \
        for (int t = aa; t < b4; t += 4) {                                     \
            const float4 w = *(const float4*)(tile + t);                       \
            const int sid = tb + t + d_;                                       \
            cnt += (int)((w.x < x) | ((w.x == x) & (sid < myid)));             \
            cnt += (int)((w.y < x) | ((w.y == x) & (sid + 1 < myid)));         \
            cnt += (int)((w.z < x) | ((w.z == x) & (sid + 2 < myid)));         \
            cnt += (int)((w.w < x) | ((w.w == x) & (sid + 3 < myid)));         \
        }                                                                      \
        for (int t = b4; t < b_; ++t) {                                        \
            const float v = tile[t]; const int sid = tb + t + d_;              \
            cnt += (int)((v < x) | ((v == x) & (sid < myid)));                 \
        }                                                                      \
    }
    K4_SEG(0, lim1, 0)
    K4_SEG(lim1, te, P - F)
#undef K4_SEG
    if (cnt) atomicAdd(&cnt4[e], cnt);
}

// ---------------- K4b: scatter evicted list + survivor flags from final ranks ----------------
__global__ __launch_bounds__(256) void k4_scatter(
    const float* __restrict__ outPrior, const float* __restrict__ cvalS,
    const int* __restrict__ writeNum, const int* __restrict__ meta, int P,
    const int* __restrict__ cnt4,
    float* __restrict__ evV, int* __restrict__ evId, int* __restrict__ survW)
{
    const int M = meta[0], F = meta[1], R = meta[2];
    if (M == 0) return;
    const int tot = F + M;
    const int e = blockIdx.x * 256 + threadIdx.x;
    if (e >= tot) return;
    float x; int myid; bool isCand = false; int wn = -1;
    if (e < F) { x = outPrior[e]; myid = e; }
    else {
        const int i = e - F;
        x = cvalS[i];
        if (x == FINF) return;
        isCand = true; wn = writeNum[i]; myid = P + i;
    }
    const int cnt = cnt4[e];
    if (isCand) survW[wn] = (cnt >= R) ? 1 : 0;
    if (cnt < R + 64) { evV[cnt] = x; evId[cnt] = isCand ? (P + wn) : myid; }
}

// ---------------- K5: chunked slot-chain resolution (exact tie handling) ----------------
#define SCAP 14400
__global__ __launch_bounds__(64, 1) void k5_chain(
    const float* __restrict__ evV, const int* __restrict__ evId,
    const int* __restrict__ meta, int P,
    int* __restrict__ Sg, int* __restrict__ survW)
{
    __shared__ int S[SCAP];
    const int lane = threadIdx.x;
    const int R = meta[2];
    if (R <= 0 || R > SCAP) return;
    const int F = meta[1];
    const int Wtot = F + R;

    // Rp: start of the equal-value run straddling the evicted/survivor boundary
    int Rp = R;
    {
        const float vR1 = evV[R - 1];
        const bool tieAtR = (R < Wtot) && (evV[R] == vR1);
        if (tieAtR) {
            const int rr = R - 1 - lane;
            const float v = (rr >= 0) ? evV[rr] : FINF;
            const u64 neq = __ballot(v != vR1);
            const int l = neq ? (__ffsll((long long)neq) - 1) : 64;
            Rp = R - l;
            if (Rp < 0) Rp = 0;
        }
    }

    // main loop over fully-evicted ranks [0, Rp), 64-ish at a time, cut at run starts
    int b = 0;
    while (b < Rp) {
        const int t = lane;
        const int r = b + t;
        const bool inW = r < Rp;
        const float val = inW ? evV[r] : FINF;
        const int id = inW ? evId[r] : 0;
        const float pv = __shfl_up(val, 1, 64);
        const bool tp = (t > 0) && inW && (val == pv);   // tied with previous rank
        const u64 starts = __ballot((!tp) && inW);
        int L;
        if (b + 64 >= Rp) L = Rp - b;
        else {
            const u64 m2 = starts & ~1ull;
            L = m2 ? (63 - __clzll((long long)m2)) : 64;  // cut at last run start
        }
        const bool active = t < L;
        const u64 activeMask = (L >= 64) ? ALL1 : ((1ull << L) - 1ull);
        const u64 sm = starts & activeMask;
        const u64 below = (2ull << t) - 1ull;             // bits 0..t (t=63 wraps to ALL1)
        const int rs = 63 - __clzll((long long)((sm & below) | 1ull));
        const u64 nxt = sm & ~below;
        const int re = nxt ? (__ffsll((long long)nxt) - 1) : L;
        const int runLen = re - rs;
        const u64 runMask = ((runLen >= 64) ? ALL1 : ((1ull << runLen) - 1ull)) << rs;

        const bool isInit = id < P;
        const int wn = id - P;                            // parent write index (if write)
        int ms = -1;                                      // member's current slot
        if (active) {
            if (isInit) ms = id;
            else if (wn < b) ms = S[wn];
        }
        int Sv = -1;                                      // assigned slot for this rank
        for (int iter = 0; iter < 80; ++iter) {
            const u64 asg = __ballot(Sv >= 0);
            if ((asg & activeMask) == activeMask) break;
            const int pl = wn - b;
            const int pS = __shfl(Sv, pl & 63, 64);
            if (active && ms < 0 && pl >= 0 && pl < 64 && ((asg >> pl) & 1ull)) ms = pS;
            const u64 msk = __ballot(ms >= 0);
            const bool ready = active && (Sv < 0) && ((msk & runMask) == runMask);
            const int maxRL = waveMaxI(ready ? runLen : 1);
            for (int ss = 0; ss < maxRL; ++ss) {          // odd-even sort run by slot
                const int po = (((t - rs) & 1) == (ss & 1)) ? (t + 1) : (t - 1);
                const int om = __shfl(ms, po & 63, 64);
                if (ready && runLen > 1 && po >= rs && po < re) {
                    ms = (po > t) ? (ms < om ? ms : om) : (ms > om ? ms : om);
                }
            }
            if (ready) Sv = ms;
        }
        if (active) { S[r] = Sv; Sg[r] = Sv; }
        b += L;
    }

    // boundary run [Rp, R): e evictions take the e smallest current slots
    if (Rp < R) {
        const int r = Rp + lane;
        const float v0 = evV[Rp];
        const bool mem = (r < Wtot) && (evV[r] == v0);
        const int g = (int)__popcll(__ballot(mem));
        const int e = R - Rp;
        int id = 0, ms = 0;
        if (mem) {
            id = evId[r];
            ms = (id < P) ? id : S[id - P];
        }
        u64 key = mem ? ((((u64)(unsigned)ms) << 32) | (u64)(unsigned)id) : ALL1;
        sort64(key, lane);
        const int sid = (int)(unsigned)(key & 0xFFFFFFFFull);
        const int sms = (int)(unsigned)(key >> 32);
        const bool real = (key != ALL1) && (lane < g);
        if (real && lane < e) { S[Rp + lane] = sms; Sg[Rp + lane] = sms; }
        if (real && sid >= P) survW[sid - P] = (lane >= e) ? 1 : 0;
    }
}

// ---------------- K5b: apply surviving writes ----------------
__global__ __launch_bounds__(256) void k5b_apply(
    const int* __restrict__ Sg, const int* __restrict__ survW,
    const float* __restrict__ wval, const int* __restrict__ wsrc,
    const int* __restrict__ meta,
    float* __restrict__ outPrior, int* __restrict__ srcWs)
{
    const int R = meta[2];
    const int j = blockIdx.x * 256 + threadIdx.x;
    if (j >= R) return;
    if (survW[j]) {
        const int s = Sg[j];
        outPrior[s] = wval[j];
        srcWs[s] = wsrc[j];
    }
}

// ---------------- gather: one block per pool row ----------------
__global__ __launch_bounds__(256) void gather_kernel(
    const float* __restrict__ summaries,
    const float* __restrict__ pool,
    const int* __restrict__ src,
    float* __restrict__ outPool, int D) {
    int p = blockIdx.x;
    int s = src[p];
    const float* row = (s >= 0) ? (summaries + (size_t)s * D) : (pool + (size_t)p * D);
    float* o = outPool + (size_t)p * D;
    if ((D & 3) == 0) {
        for (int k = (threadIdx.x << 2); k < D; k += (blockDim.x << 2)) {
            float4 v = *(const float4*)(row + k);
            *(float4*)(o + k) = v;
        }
    } else {
        for (int k = threadIdx.x; k < D; k += blockDim.x) o[k] = row[k];
    }
}

extern "C" void kernel_launch(void* const* d_in, const int* in_sizes, int n_in,
                              void* d_out, int out_size, void* d_ws, size_t ws_size,
                              hipStream_t stream) {
    const float* summaries  = (const float*)d_in[0];
    const float* scores     = (const float*)d_in[1];
    const float* pool       = (const float*)d_in[2];
    const float* priorities = (const float*)d_in[3];
    const int*   count      = (const int*)d_in[4];

    int N = in_sizes[1];            // 16384
    int P = in_sizes[3];            // 4096
    int D = in_sizes[0] / N;        // 1024

    float* outPool  = (float*)d_out;
    float* outPrior = outPool + (size_t)P * D;
    float* outCnt   = outPrior + P;
    int*   srcWs    = (int*)d_ws;   // P ints; must survive into gather

    // scratch lives inside outPool: gather fully overwrites it at the end
    float* cval     = outPool;
    int*   csrc     = (int*)outPool + 1 * N;
    float* cvalS    = outPool + 3 * N;
    float* wval     = outPool + 4 * N;
    int*   wsrc     = (int*)outPool + 5 * N;
    int*   writeNum = (int*)outPool + 6 * N;
    float* evV      = outPool + 7 * N;                 // N + 64
    int*   evId     = (int*)outPool + 8 * N + 64;      // N + 64
    int*   Sgbuf    = (int*)outPool + 9 * N + 128;     // N
    int*   survW    = (int*)outPool + 10 * N + 128;    // N
    int*   meta     = (int*)outPool + 11 * N + 128;    // 8
    int*   cnt2     = (int*)outPool + 11 * N + 192;    // N
    int*   cnt4     = (int*)outPool + 12 * N + 192;    // P + N

    const int nb2 = (N + 255) / 256;
    const int nb4 = (P + N + 255) / 256;
    const int ty  = (P + N + K2T - 1) / K2T;

    dim3 g2(nb2, ty), g4(nb4, ty);

    k1_scan<<<1, 1024, 0, stream>>>(scores, priorities, count, N, P,
                                    outPrior, outCnt, srcWs, cval, csrc, meta,
                                    cnt2, cnt4);
    k2_count<<<g2, 256, 0, stream>>>(outPrior, cval, meta, cnt2);
    k3_compact<<<1, 1024, 0, stream>>>(cval, csrc, cnt2, meta, cvalS, wval, wsrc, writeNum);
    k4_count<<<g4, 256, 0, stream>>>(outPrior, cvalS, meta, P, cnt4);
    k4_scatter<<<nb4, 256, 0, stream>>>(outPrior, cvalS, writeNum, meta, P, cnt4,
                                        evV, evId, survW);
    k5_chain<<<1, 64, 0, stream>>>(evV, evId, meta, P, Sgbuf, survW);
    k5b_apply<<<nb2, 256, 0, stream>>>(Sgbuf, survW, wval, wsrc, meta, outPrior, srcWs);
    gather_kernel<<<P, 256, 0, stream>>>(summaries, pool, srcWs, outPool, D);
}

// Round 3
// 218.544 us; speedup vs baseline: 4.3979x; 1.2827x over previous
//
#include <hip/hip_runtime.h>

typedef unsigned long long u64;
#define THRESH 0.5f
#define ALL1 0xFFFFFFFFFFFFFFFFull
#define FINF __builtin_inff()

__device__ __forceinline__ u64 shflxU64(u64 v, int m) { return __shfl_xor(v, m, 64); }
// Full bitonic sort of 64 u64 keys (one per lane), ascending across lanes.
__device__ __forceinline__ void sort64(u64 &key, int lane) {
#pragma unroll
    for (int k = 2; k <= 64; k <<= 1) {
#pragma unroll
        for (int j = k >> 1; j > 0; j >>= 1) {
            u64 p = shflxU64(key, j);
            bool takeMax = ((lane & j) != 0) != ((lane & k) != 0);
            u64 mn = key < p ? key : p;
            u64 mx = key < p ? p : key;
            key = takeMax ? mx : mn;
        }
    }
}

// ---------------- K1: valid scan, appends, candidate compaction, cnt zeroing ----------------
__global__ __launch_bounds__(1024) void k1_scan(
    const float* __restrict__ scores, const float* __restrict__ priorities,
    const int* __restrict__ countPtr, int N, int P,
    float* __restrict__ outPrior, float* __restrict__ outCnt, int* __restrict__ srcWs,
    float* __restrict__ cval, int* __restrict__ csrc, int* __restrict__ meta,
    int* __restrict__ cnt2, int* __restrict__ cnt4)
{
    const int tid = threadIdx.x;
    for (int s = tid; s < P; s += 1024) { outPrior[s] = priorities[s]; srcWs[s] = -1; }
    for (int s = tid; s < N; s += 1024) cnt2[s] = 0;
    for (int s = tid; s < P + N; s += 1024) cnt4[s] = 0;
    int C0 = *countPtr; C0 = C0 < 0 ? 0 : (C0 > P ? P : C0);
    const int per = (N + 1023) >> 10;
    const int i0 = tid * per;
    const int i1 = min(i0 + per, N);
    int c = 0;
    for (int i = i0; i < i1; ++i) c += (scores[i] > THRESH) ? 1 : 0;
    __shared__ int sb[1024];
    sb[tid] = c; __syncthreads();
    for (int off = 1; off < 1024; off <<= 1) {
        int v = (tid >= off) ? sb[tid - off] : 0;
        __syncthreads();
        sb[tid] += v;
        __syncthreads();
    }
    const int total = sb[1023];
    int v = sb[tid] - c;  // exclusive prefix of valid count
    int A = P - C0; if (A > total) A = total; if (A < 0) A = 0;
    for (int i = i0; i < i1; ++i) {
        float sc = scores[i];
        if (sc > THRESH) {
            if (v < A) { outPrior[C0 + v] = sc; srcWs[C0 + v] = i; }
            else { cval[v - A] = sc; csrc[v - A] = i; }
            ++v;
        }
    }
    if (tid == 0) {
        meta[0] = total - A;      // M: number of replacement candidates
        meta[1] = C0 + A;         // F: filled pool size after appends
        outCnt[0] = (float)(C0 + A);
    }
}

// ---------------- K2: split dominance count for success condition ----------------
#define K2T 1024
__global__ __launch_bounds__(256) void k2_count(
    const float* __restrict__ outPrior, const float* __restrict__ cval,
    const int* __restrict__ meta, int* __restrict__ cnt2)
{
    const int M = meta[0], F = meta[1];
    const int iB = blockIdx.x << 8;
    if (iB >= M) return;
    const int hi = min(M, iB + 256);
    const int totSrc = F + hi;            // sources possibly needed by this block
    const int tb = blockIdx.y * K2T;
    if (tb >= totSrc) return;
    const int te = min(totSrc - tb, K2T);
    const int i = iB + threadIdx.x;
    const bool live = i < M;
    const float x = live ? cval[i] : 0.f;
    __shared__ __align__(16) float tile[K2T];
    for (int t = threadIdx.x; t < K2T; t += 256) {
        const int s = tb + t;
        tile[t] = (t < te) ? ((s < F) ? outPrior[s] : cval[s - F]) : FINF;
    }
    __syncthreads();
    if (!live) return;
    int lim = F + i - tb;
    if (lim < 0) lim = 0;
    if (lim > te) lim = te;
    int cnt = 0;
    const int l4 = lim >> 2;
    const float4* t4 = (const float4*)tile;
    for (int q = 0; q < l4; ++q) {
        const float4 w = t4[q];
        cnt += (w.x < x) + (w.y < x) + (w.z < x) + (w.w < x);
    }
    for (int t = l4 << 2; t < lim; ++t) cnt += tile[t] < x;
    if (cnt) atomicAdd(&cnt2[i], cnt);
}

// ---------------- K3: succ from cnt2, scan -> write numbers, compact writes ----------------
__global__ __launch_bounds__(1024) void k3_compact(
    const float* __restrict__ cval, const int* __restrict__ csrc,
    const int* __restrict__ cnt2, int* __restrict__ meta,
    float* __restrict__ cvalS, float* __restrict__ wval, int* __restrict__ wsrc,
    int* __restrict__ writeNum)
{
    const int M = meta[0];
    const int tid = threadIdx.x;
    const int per = (M + 1023) >> 10;
    const int i0 = tid * per, i1 = min(i0 + per, M);
    int c = 0;
    for (int i = i0; i < i1; ++i) c += (cnt2[i] >= i + 1) ? 1 : 0;
    __shared__ int sb[1024];
    sb[tid] = c; __syncthreads();
    for (int off = 1; off < 1024; off <<= 1) {
        int v = (tid >= off) ? sb[tid - off] : 0;
        __syncthreads();
        sb[tid] += v;
        __syncthreads();
    }
    int w = sb[tid] - c;
    for (int i = i0; i < i1; ++i) {
        if (cnt2[i] >= i + 1) {
            wval[w] = cval[i]; wsrc[w] = csrc[i]; writeNum[i] = w; cvalS[i] = cval[i]; ++w;
        } else { writeNum[i] = -1; cvalS[i] = FINF; }
    }
    if (tid == 0) meta[2] = sb[1023];   // R: number of successful writes
}

// ---------------- K4a: split rank count in W = V ∪ C_succ, (value,id) keys ----------------
#define K4T 1024
__global__ __launch_bounds__(256) void k4_count(
    const float* __restrict__ outPrior, const float* __restrict__ cvalS,
    const int* __restrict__ meta, int P, int* __restrict__ cnt4)
{
    const int M = meta[0], F = meta[1];
    if (M == 0) return;
    const int tot = F + M;
    const int eB = blockIdx.x << 8;
    if (eB >= tot) return;
    const int tb = blockIdx.y * K4T;
    if (tb >= tot) return;
    const int te = min(tot - tb, K4T);
    const int e = eB + threadIdx.x;
    bool live = e < tot;
    float x = 0.f; int myid = 0;
    if (live) {
        if (e < F) { x = outPrior[e]; myid = e; }
        else {
            x = cvalS[e - F]; myid = P + (e - F);
            if (x == FINF) live = false;
        }
    }
    __shared__ __align__(16) float tile[K4T];
    for (int t = threadIdx.x; t < K4T; t += 256) {
        const int s = tb + t;
        tile[t] = (t < te) ? ((s < F) ? outPrior[s] : cvalS[s - F]) : FINF;
    }
    __syncthreads();
    if (!live) return;
    int cnt = 0;
    int lim1 = F - tb;                   // tile-local boundary pool|candidates
    if (lim1 < 0) lim1 = 0;
    if (lim1 > te) lim1 = te;
#define K4_SEG(a, b, d)                                                        \
    {                                                                          \
        const int a_ = (a), b_ = (b), d_ = (d);                                \
        int aa = (a_ + 3) & ~3; if (aa > b_) aa = b_;                          \
        for (int t = a_; t < aa; ++t) {                                        \
            const float v = tile[t]; const int sid = tb + t + d_;              \
            cnt += (int)((v < x) | ((v == x) & (sid < myid)));                 \
        }                                                                      \
        const int b4 = aa + (((b_ - aa) >> 2) << 2);                           \
        for (int t = aa; t < b4; t += 4) {                                     \
            const float4 w = *(const float4*)(tile + t);                       \
            const int sid = tb + t + d_;                                       \
            cnt += (int)((w.x < x) | ((w.x == x) & (sid < myid)));             \
            cnt += (int)((w.y < x) | ((w.y == x) & (sid + 1 < myid)));         \
            cnt += (int)((w.z < x) | ((w.z == x) & (sid + 2 < myid)));         \
            cnt += (int)((w.w < x) | ((w.w == x) & (sid + 3 < myid)));         \
        }                                                                      \
        for (int t = b4; t < b_; ++t) {                                        \
            const float v = tile[t]; const int sid = tb + t + d_;              \
            cnt += (int)((v < x) | ((v == x) & (sid < myid)));                 \
        }                                                                      \
    }
    K4_SEG(0, lim1, 0)
    K4_SEG(lim1, te, P - F)
#undef K4_SEG
    if (cnt) atomicAdd(&cnt4[e], cnt);
}

// ---------------- K4b: scatter evicted list + survivor flags from final ranks ----------------
__global__ __launch_bounds__(256) void k4_scatter(
    const float* __restrict__ outPrior, const float* __restrict__ cvalS,
    const int* __restrict__ writeNum, const int* __restrict__ meta, int P,
    const int* __restrict__ cnt4,
    float* __restrict__ evV, int* __restrict__ evId, int* __restrict__ survW)
{
    const int M = meta[0], F = meta[1], R = meta[2];
    if (M == 0) return;
    const int tot = F + M;
    const int e = blockIdx.x * 256 + threadIdx.x;
    if (e >= tot) return;
    float x; int myid; bool isCand = false; int wn = -1;
    if (e < F) { x = outPrior[e]; myid = e; }
    else {
        const int i = e - F;
        x = cvalS[i];
        if (x == FINF) return;
        isCand = true; wn = writeNum[i]; myid = P + i;
    }
    const int cnt = cnt4[e];
    if (isCand) survW[wn] = (cnt >= R) ? 1 : 0;
    if (cnt < R + 64) { evV[cnt] = x; evId[cnt] = isCand ? (P + wn) : myid; }
}

// ---------------- K5: parallel slot-chain resolution (walk-to-root + tie rounds) ------------
// Rank r's slot: evId[r] if initial, else slot of write wn=evId[r]-P, which is
// S[wn] (rank-indexed; write j replaces eviction j). Parents are in strictly
// earlier value-runs, so chains through untied ranks resolve by a direct walk;
// tied runs (equal values) are assigned by sorting member slots ascending once
// all members are known. Boundary run straddling R keeps exact semantics.
#define SCAP 14400
#define MSF   (1 << 29)
#define DONEF (1 << 30)
#define SLOTM ((1 << 29) - 1)
__global__ __launch_bounds__(1024) void k5_chain(
    const float* __restrict__ evV, const int* __restrict__ evId,
    const int* __restrict__ meta, int P,
    int* __restrict__ Sg, int* __restrict__ survW)
{
    __shared__ int state[SCAP];
    __shared__ int shRp, shLeft;
    const int tid = threadIdx.x;
    const int R = meta[2];
    if (R <= 0 || R > SCAP) return;
    const int F = meta[1];
    const int Wtot = F + R;

    // Rp: start of the equal-value run straddling the evicted/survivor boundary
    if (tid == 0) {
        int Rp = R;
        if (R < Wtot) {
            const float vR1 = evV[R - 1];
            if (evV[R] == vR1) {
                int rr = R - 1;
                while (rr >= 0 && evV[rr] == vR1) --rr;
                Rp = rr + 1;
            }
        }
        shRp = Rp;
    }
    __syncthreads();
    const int Rp = shRp;

    for (int r = tid; r < Rp; r += 1024) state[r] = 0;
    __syncthreads();

    for (int round = 0; round < Rp + 2; ++round) {
        // resolve phase: walk chains through untied ancestors to a root/DONE
        for (int r = tid; r < Rp; r += 1024) {
            if (state[r] & (DONEF | MSF)) continue;
            int cur = r, ms = -1;
            while (true) {
                const int id = evId[cur];
                if (id < P) { ms = id; break; }
                const int p = id - P;
                if (p >= cur || p < 0) break;              // malformed guard
                const int sp = state[p];
                if (sp & DONEF) { ms = sp & SLOTM; break; }
                const float v = evV[p];
                const bool tiedP = (p > 0 && evV[p - 1] == v) ||
                                   (p + 1 < Rp && evV[p + 1] == v);
                if (tiedP) break;                          // wait for run assignment
                cur = p;                                   // untied: slot passes through
            }
            if (ms >= 0) {
                const float v = evV[r];
                const bool tiedR = (r > 0 && evV[r - 1] == v) ||
                                   (r + 1 < Rp && evV[r + 1] == v);
                state[r] = ms | (tiedR ? MSF : (MSF | DONEF));
            }
        }
        __syncthreads();
        // tied-run assignment: leader = run start; sort member slots ascending
        for (int r = tid; r < Rp; r += 1024) {
            const float v = evV[r];
            if (r > 0 && evV[r - 1] == v) continue;        // not run start
            if (r + 1 >= Rp || evV[r + 1] != v) continue;  // run length 1
            if (state[r] & DONEF) continue;                // already assigned
            int re = r + 1;
            while (re < Rp && evV[re] == v) ++re;
            bool ready = true;
            for (int s = r; s < re; ++s) ready &= (state[s] & MSF) != 0;
            if (!ready) continue;
            for (int j = r; j < re; ++j) {                 // in-place selection sort
                int best = j;
                for (int s = j + 1; s < re; ++s)
                    if ((state[s] & SLOTM) < (state[best] & SLOTM)) best = s;
                const int tmp = state[best];
                state[best] = state[j];
                state[j] = tmp;
            }
            for (int j = r; j < re; ++j) state[j] |= DONEF;
        }
        __syncthreads();
        if (tid == 0) shLeft = 0;
        __syncthreads();
        int loc = 0;
        for (int r = tid; r < Rp; r += 1024) loc += (state[r] & DONEF) ? 0 : 1;
        if (loc) atomicAdd(&shLeft, loc);
        __syncthreads();
        if (shLeft == 0) break;
    }

    for (int r = tid; r < Rp; r += 1024) Sg[r] = state[r] & SLOTM;
    __syncthreads();

    // boundary run [Rp, R): e evictions take the e smallest current slots
    if (Rp < R && tid < 64) {
        const int lane = tid;
        const int r = Rp + lane;
        const float v0 = evV[Rp];
        const bool mem = (r < Wtot) && (evV[r] == v0);
        const int g = (int)__popcll(__ballot(mem));
        const int e = R - Rp;
        int id = 0, ms = 0;
        if (mem) {
            id = evId[r];
            ms = (id < P) ? id : (state[id - P] & SLOTM);
        }
        u64 key = mem ? ((((u64)(unsigned)ms) << 32) | (u64)(unsigned)id) : ALL1;
        sort64(key, lane);
        const int sid = (int)(unsigned)(key & 0xFFFFFFFFull);
        const int sms = (int)(unsigned)(key >> 32);
        const bool real = (key != ALL1) && (lane < g);
        if (real && lane < e) Sg[Rp + lane] = sms;
        if (real && sid >= P) survW[sid - P] = (lane >= e) ? 1 : 0;
    }
}

// ---------------- K5b: apply surviving writes ----------------
__global__ __launch_bounds__(256) void k5b_apply(
    const int* __restrict__ Sg, const int* __restrict__ survW,
    const float* __restrict__ wval, const int* __restrict__ wsrc,
    const int* __restrict__ meta,
    float* __restrict__ outPrior, int* __restrict__ srcWs)
{
    const int R = meta[2];
    const int j = blockIdx.x * 256 + threadIdx.x;
    if (j >= R) return;
    if (survW[j]) {
        const int s = Sg[j];
        outPrior[s] = wval[j];
        srcWs[s] = wsrc[j];
    }
}

// ---------------- gather: one block per pool row ----------------
__global__ __launch_bounds__(256) void gather_kernel(
    const float* __restrict__ summaries,
    const float* __restrict__ pool,
    const int* __restrict__ src,
    float* __restrict__ outPool, int D) {
    int p = blockIdx.x;
    int s = src[p];
    const float* row = (s >= 0) ? (summaries + (size_t)s * D) : (pool + (size_t)p * D);
    float* o = outPool + (size_t)p * D;
    if ((D & 3) == 0) {
        for (int k = (threadIdx.x << 2); k < D; k += (blockDim.x << 2)) {
            float4 v = *(const float4*)(row + k);
            *(float4*)(o + k) = v;
        }
    } else {
        for (int k = threadIdx.x; k < D; k += blockDim.x) o[k] = row[k];
    }
}

extern "C" void kernel_launch(void* const* d_in, const int* in_sizes, int n_in,
                              void* d_out, int out_size, void* d_ws, size_t ws_size,
                              hipStream_t stream) {
    const float* summaries  = (const float*)d_in[0];
    const float* scores     = (const float*)d_in[1];
    const float* pool       = (const float*)d_in[2];
    const float* priorities = (const float*)d_in[3];
    const int*   count      = (const int*)d_in[4];

    int N = in_sizes[1];            // 16384
    int P = in_sizes[3];            // 4096
    int D = in_sizes[0] / N;        // 1024

    float* outPool  = (float*)d_out;
    float* outPrior = outPool + (size_t)P * D;
    float* outCnt   = outPrior + P;
    int*   srcWs    = (int*)d_ws;   // P ints; must survive into gather

    // scratch lives inside outPool: gather fully overwrites it at the end
    float* cval     = outPool;
    int*   csrc     = (int*)outPool + 1 * N;
    float* cvalS    = outPool + 3 * N;
    float* wval     = outPool + 4 * N;
    int*   wsrc     = (int*)outPool + 5 * N;
    int*   writeNum = (int*)outPool + 6 * N;
    float* evV      = outPool + 7 * N;                 // N + 64
    int*   evId     = (int*)outPool + 8 * N + 64;      // N + 64
    int*   Sgbuf    = (int*)outPool + 9 * N + 128;     // N
    int*   survW    = (int*)outPool + 10 * N + 128;    // N
    int*   meta     = (int*)outPool + 11 * N + 128;    // 8
    int*   cnt2     = (int*)outPool + 11 * N + 192;    // N
    int*   cnt4     = (int*)outPool + 12 * N + 192;    // P + N

    const int nb2 = (N + 255) / 256;
    const int nb4 = (P + N + 255) / 256;
    const int ty  = (P + N + K2T - 1) / K2T;

    dim3 g2(nb2, ty), g4(nb4, ty);

    k1_scan<<<1, 1024, 0, stream>>>(scores, priorities, count, N, P,
                                    outPrior, outCnt, srcWs, cval, csrc, meta,
                                    cnt2, cnt4);
    k2_count<<<g2, 256, 0, stream>>>(outPrior, cval, meta, cnt2);
    k3_compact<<<1, 1024, 0, stream>>>(cval, csrc, cnt2, meta, cvalS, wval, wsrc, writeNum);
    k4_count<<<g4, 256, 0, stream>>>(outPrior, cvalS, meta, P, cnt4);
    k4_scatter<<<nb4, 256, 0, stream>>>(outPrior, cvalS, writeNum, meta, P, cnt4,
                                        evV, evId, survW);
    k5_chain<<<1, 1024, 0, stream>>>(evV, evId, meta, P, Sgbuf, survW);
    k5b_apply<<<nb2, 256, 0, stream>>>(Sgbuf, survW, wval, wsrc, meta, outPrior, srcWs);
    gather_kernel<<<P, 256, 0, stream>>>(summaries, pool, srcWs, outPool, D);
}

// Round 4
// 181.733 us; speedup vs baseline: 5.2888x; 1.2026x over previous
//
#include <hip/hip_runtime.h>

typedef unsigned long long u64;
#define THRESH 0.5f
#define ALL1 0xFFFFFFFFFFFFFFFFull
#define FINF __builtin_inff()

__device__ __forceinline__ u64 shflxU64(u64 v, int m) { return __shfl_xor(v, m, 64); }
// Full bitonic sort of 64 u64 keys (one per lane), ascending across lanes.
__device__ __forceinline__ void sort64(u64 &key, int lane) {
#pragma unroll
    for (int k = 2; k <= 64; k <<= 1) {
#pragma unroll
        for (int j = k >> 1; j > 0; j >>= 1) {
            u64 p = shflxU64(key, j);
            bool takeMax = ((lane & j) != 0) != ((lane & k) != 0);
            u64 mn = key < p ? key : p;
            u64 mx = key < p ? p : key;
            key = takeMax ? mx : mn;
        }
    }
}

// Monotonic (value,id) key: float -> order-preserving u32 (with -0 canonicalized
// to +0 so float equality == key equality), id in low 32 bits as tiebreak.
__device__ __forceinline__ u64 mkey(float v, int id) {
    v = (v == 0.0f) ? 0.0f : v;                 // -0 -> +0
    unsigned u = __float_as_uint(v);
    u ^= (unsigned)((int)u >> 31) | 0x80000000u;
    return ((u64)u << 32) | (unsigned)id;
}

// ---------------- K1: valid scan, appends, candidate compaction ----------------
__global__ __launch_bounds__(1024) void k1_scan(
    const float* __restrict__ scores, const float* __restrict__ priorities,
    const int* __restrict__ countPtr, int N, int P,
    float* __restrict__ outPrior, float* __restrict__ outCnt, int* __restrict__ srcWs,
    float* __restrict__ cval, int* __restrict__ csrc, int* __restrict__ meta)
{
    const int tid = threadIdx.x;
    for (int s = tid; s < P; s += 1024) { outPrior[s] = priorities[s]; srcWs[s] = -1; }
    int C0 = *countPtr; C0 = C0 < 0 ? 0 : (C0 > P ? P : C0);
    const int per = (N + 1023) >> 10;
    const int i0 = tid * per;
    float sv[16];
    if (per == 16 && i0 + 16 <= N) {
        const float4* s4 = (const float4*)(scores + i0);
        const float4 a = s4[0], b = s4[1], c4 = s4[2], d = s4[3];
        sv[0]=a.x; sv[1]=a.y; sv[2]=a.z; sv[3]=a.w;
        sv[4]=b.x; sv[5]=b.y; sv[6]=b.z; sv[7]=b.w;
        sv[8]=c4.x; sv[9]=c4.y; sv[10]=c4.z; sv[11]=c4.w;
        sv[12]=d.x; sv[13]=d.y; sv[14]=d.z; sv[15]=d.w;
    } else {
#pragma unroll 16
        for (int j = 0; j < 16; ++j)
            sv[j] = (j < per && i0 + j < N) ? scores[i0 + j] : 0.f;
    }
    int c = 0;
#pragma unroll 16
    for (int j = 0; j < 16; ++j) c += (j < per && i0 + j < N && sv[j] > THRESH) ? 1 : 0;
    __shared__ int sb[1024];
    sb[tid] = c; __syncthreads();
    for (int off = 1; off < 1024; off <<= 1) {
        int v = (tid >= off) ? sb[tid - off] : 0;
        __syncthreads();
        sb[tid] += v;
        __syncthreads();
    }
    const int total = sb[1023];
    int v = sb[tid] - c;  // exclusive prefix of valid count
    int A = P - C0; if (A > total) A = total; if (A < 0) A = 0;
#pragma unroll 16
    for (int j = 0; j < 16; ++j) {
        if (j < per && i0 + j < N) {
            const float sc = sv[j];
            if (sc > THRESH) {
                if (v < A) { outPrior[C0 + v] = sc; srcWs[C0 + v] = i0 + j; }
                else { cval[v - A] = sc; csrc[v - A] = i0 + j; }
                ++v;
            }
        }
    }
    if (tid == 0) {
        meta[0] = total - A;      // M: number of replacement candidates
        meta[1] = C0 + A;         // F: filled pool size after appends
        outCnt[0] = (float)(C0 + A);
    }
}

// ---------------- K2: split dominance count for success condition ----------------
// cnt2[i] = #{V < c_i} + #{j<i : c_j < c_i}; cand i succeeds iff cnt2[i] >= i+1.
#define K2T 512
__global__ __launch_bounds__(256) void k2_count(
    const float* __restrict__ outPrior, const float* __restrict__ cval,
    const int* __restrict__ meta, int* __restrict__ cnt2)
{
    const int M = meta[0], F = meta[1];
    const int iB = blockIdx.x << 8;
    if (iB >= M) return;
    const int hi = min(M, iB + 256);
    const int smax = F + hi;              // exclusive max source index this block needs
    const int tb = blockIdx.y * K2T;
    if (tb >= smax) return;
    const int te = min(smax - tb, K2T);
    __shared__ __align__(16) float tile[K2T];
    for (int t = threadIdx.x; t < K2T; t += 256) {
        const int s = tb + t;
        tile[t] = (t < te) ? ((s < F) ? outPrior[s] : cval[s - F]) : FINF;
    }
    __syncthreads();
    const int i = iB + threadIdx.x;
    if (i >= M) return;
    const float x = cval[i];
    int cnt = 0;
    const float4* t4 = (const float4*)tile;
    if (tb + K2T <= F + iB) {             // full tile for every thread in block
#pragma unroll 8
        for (int q = 0; q < K2T / 4; ++q) {
            const float4 w = t4[q];
            cnt += (w.x < x) + (w.y < x) + (w.z < x) + (w.w < x);
        }
    } else {
        int lim = F + i - tb;
        if (lim < 0) lim = 0;
        if (lim > te) lim = te;
        const int l4 = lim >> 2;
        for (int q = 0; q < l4; ++q) {
            const float4 w = t4[q];
            cnt += (w.x < x) + (w.y < x) + (w.z < x) + (w.w < x);
        }
        for (int t = l4 << 2; t < lim; ++t) cnt += tile[t] < x;
    }
    if (cnt) atomicAdd(&cnt2[i], cnt);
}

// ---------------- K3: succ from cnt2, scan -> write numbers, compact writes ----------------
__global__ __launch_bounds__(1024) void k3_compact(
    const float* __restrict__ cval, const int* __restrict__ csrc,
    const int* __restrict__ cnt2, int* __restrict__ meta,
    float* __restrict__ cvalS, float* __restrict__ wval, int* __restrict__ wsrc,
    int* __restrict__ writeNum)
{
    const int M = meta[0];
    const int tid = threadIdx.x;
    const int per = (M + 1023) >> 10;
    const int i0 = tid * per, i1 = min(i0 + per, M);
    int c = 0;
    for (int i = i0; i < i1; ++i) c += (cnt2[i] >= i + 1) ? 1 : 0;
    __shared__ int sb[1024];
    sb[tid] = c; __syncthreads();
    for (int off = 1; off < 1024; off <<= 1) {
        int v = (tid >= off) ? sb[tid - off] : 0;
        __syncthreads();
        sb[tid] += v;
        __syncthreads();
    }
    int w = sb[tid] - c;
    for (int i = i0; i < i1; ++i) {
        if (cnt2[i] >= i + 1) {
            wval[w] = cval[i]; wsrc[w] = csrc[i]; writeNum[i] = w; cvalS[i] = cval[i]; ++w;
        } else { writeNum[i] = -1; cvalS[i] = FINF; }
    }
    if (tid == 0) meta[2] = sb[1023];   // R: number of successful writes
}

// ---------------- K4a: rank count in W = V ∪ C_succ via u64 monotonic keys ----------------
// Key = (mono(value)<<32)|id, id = s<F ? s : P+(s-F). One u64 compare replaces
// the (v<x)|((v==x)&(sid<myid)) tiebreak. Fixed 512-source trip; ALL1 padding.
#define K4T 512
__global__ __launch_bounds__(256) void k4_count(
    const float* __restrict__ outPrior, const float* __restrict__ cvalS,
    const int* __restrict__ meta, int P, int* __restrict__ cnt4)
{
    const int M = meta[0], F = meta[1];
    if (M == 0) return;
    const int tot = F + M;
    const int eB = blockIdx.x << 8;
    if (eB >= tot) return;
    const int tb = blockIdx.y * K4T;
    if (tb >= tot) return;
    const int te = min(tot - tb, K4T);
    __shared__ __align__(16) u64 tile[K4T];
    for (int t = threadIdx.x; t < K4T; t += 256) {
        const int s = tb + t;
        u64 kk = ALL1;
        if (t < te) {
            if (s < F) kk = mkey(outPrior[s], s);
            else       kk = mkey(cvalS[s - F], P + (s - F));
        }
        tile[t] = kk;
    }
    __syncthreads();
    const int e = eB + threadIdx.x;
    if (e >= tot) return;
    float x; int id;
    if (e < F) { x = outPrior[e]; id = e; }
    else {
        x = cvalS[e - F];
        if (x == FINF) return;
        id = P + (e - F);
    }
    const u64 kx = mkey(x, id);
    int cnt = 0;
    const ulonglong2* t2 = (const ulonglong2*)tile;
#pragma unroll 8
    for (int q = 0; q < K4T / 2; ++q) {
        const ulonglong2 w = t2[q];
        cnt += (int)(w.x < kx) + (int)(w.y < kx);
    }
    if (cnt) atomicAdd(&cnt4[e], cnt);
}

// ---------------- K4b: scatter evicted list + survivor flags from final ranks ----------------
__global__ __launch_bounds__(256) void k4_scatter(
    const float* __restrict__ outPrior, const float* __restrict__ cvalS,
    const int* __restrict__ writeNum, const int* __restrict__ meta, int P,
    const int* __restrict__ cnt4,
    float* __restrict__ evV, int* __restrict__ evId, int* __restrict__ survW)
{
    const int M = meta[0], F = meta[1], R = meta[2];
    if (M == 0) return;
    const int tot = F + M;
    const int e = blockIdx.x * 256 + threadIdx.x;
    if (e >= tot) return;
    float x; int myid; bool isCand = false; int wn = -1;
    if (e < F) { x = outPrior[e]; myid = e; }
    else {
        const int i = e - F;
        x = cvalS[i];
        if (x == FINF) return;
        isCand = true; wn = writeNum[i]; myid = P + i;
    }
    const int cnt = cnt4[e];
    if (isCand) survW[wn] = (cnt >= R) ? 1 : 0;
    if (cnt < R + 64) { evV[cnt] = x; evId[cnt] = isCand ? (P + wn) : myid; }
}

// ---------------- K5: parallel slot-chain resolution (walk-to-root + tie rounds) ------------
#define SCAP 14400
#define MSF   (1 << 29)
#define DONEF (1 << 30)
#define SLOTM ((1 << 29) - 1)
__global__ __launch_bounds__(1024) void k5_chain(
    const float* __restrict__ evV, const int* __restrict__ evId,
    const int* __restrict__ meta, int P,
    int* __restrict__ Sg, int* __restrict__ survW)
{
    __shared__ int state[SCAP];
    __shared__ int shRp, shLeft;
    const int tid = threadIdx.x;
    const int R = meta[2];
    if (R <= 0 || R > SCAP) return;
    const int F = meta[1];
    const int Wtot = F + R;

    if (tid == 0) {
        int Rp = R;
        if (R < Wtot) {
            const float vR1 = evV[R - 1];
            if (evV[R] == vR1) {
                int rr = R - 1;
                while (rr >= 0 && evV[rr] == vR1) --rr;
                Rp = rr + 1;
            }
        }
        shRp = Rp;
    }
    __syncthreads();
    const int Rp = shRp;

    for (int r = tid; r < Rp; r += 1024) state[r] = 0;
    __syncthreads();

    for (int round = 0; round < Rp + 2; ++round) {
        for (int r = tid; r < Rp; r += 1024) {
            if (state[r] & (DONEF | MSF)) continue;
            int cur = r, ms = -1;
            while (true) {
                const int id = evId[cur];
                if (id < P) { ms = id; break; }
                const int p = id - P;
                if (p >= cur || p < 0) break;
                const int sp = state[p];
                if (sp & DONEF) { ms = sp & SLOTM; break; }
                const float v = evV[p];
                const bool tiedP = (p > 0 && evV[p - 1] == v) ||
                                   (p + 1 < Rp && evV[p + 1] == v);
                if (tiedP) break;
                cur = p;
            }
            if (ms >= 0) {
                const float v = evV[r];
                const bool tiedR = (r > 0 && evV[r - 1] == v) ||
                                   (r + 1 < Rp && evV[r + 1] == v);
                state[r] = ms | (tiedR ? MSF : (MSF | DONEF));
            }
        }
        __syncthreads();
        for (int r = tid; r < Rp; r += 1024) {
            const float v = evV[r];
            if (r > 0 && evV[r - 1] == v) continue;
            if (r + 1 >= Rp || evV[r + 1] != v) continue;
            if (state[r] & DONEF) continue;
            int re = r + 1;
            while (re < Rp && evV[re] == v) ++re;
            bool ready = true;
            for (int s = r; s < re; ++s) ready &= (state[s] & MSF) != 0;
            if (!ready) continue;
            for (int j = r; j < re; ++j) {
                int best = j;
                for (int s = j + 1; s < re; ++s)
                    if ((state[s] & SLOTM) < (state[best] & SLOTM)) best = s;
                const int tmp = state[best];
                state[best] = state[j];
                state[j] = tmp;
            }
            for (int j = r; j < re; ++j) state[j] |= DONEF;
        }
        __syncthreads();
        if (tid == 0) shLeft = 0;
        __syncthreads();
        int loc = 0;
        for (int r = tid; r < Rp; r += 1024) loc += (state[r] & DONEF) ? 0 : 1;
        if (loc) atomicAdd(&shLeft, loc);
        __syncthreads();
        if (shLeft == 0) break;
    }

    for (int r = tid; r < Rp; r += 1024) Sg[r] = state[r] & SLOTM;
    __syncthreads();

    if (Rp < R && tid < 64) {
        const int lane = tid;
        const int r = Rp + lane;
        const float v0 = evV[Rp];
        const bool mem = (r < Wtot) && (evV[r] == v0);
        const int g = (int)__popcll(__ballot(mem));
        const int e = R - Rp;
        int id = 0, ms = 0;
        if (mem) {
            id = evId[r];
            ms = (id < P) ? id : (state[id - P] & SLOTM);
        }
        u64 key = mem ? ((((u64)(unsigned)ms) << 32) | (u64)(unsigned)id) : ALL1;
        sort64(key, lane);
        const int sid = (int)(unsigned)(key & 0xFFFFFFFFull);
        const int sms = (int)(unsigned)(key >> 32);
        const bool real = (key != ALL1) && (lane < g);
        if (real && lane < e) Sg[Rp + lane] = sms;
        if (real && sid >= P) survW[sid - P] = (lane >= e) ? 1 : 0;
    }
}

// ---------------- K5b: apply surviving writes ----------------
__global__ __launch_bounds__(256) void k5b_apply(
    const int* __restrict__ Sg, const int* __restrict__ survW,
    const float* __restrict__ wval, const int* __restrict__ wsrc,
    const int* __restrict__ meta,
    float* __restrict__ outPrior, int* __restrict__ srcWs)
{
    const int R = meta[2];
    const int j = blockIdx.x * 256 + threadIdx.x;
    if (j >= R) return;
    if (survW[j]) {
        const int s = Sg[j];
        outPrior[s] = wval[j];
        srcWs[s] = wsrc[j];
    }
}

// ---------------- gather: one block per pool row ----------------
__global__ __launch_bounds__(256) void gather_kernel(
    const float* __restrict__ summaries,
    const float* __restrict__ pool,
    const int* __restrict__ src,
    float* __restrict__ outPool, int D) {
    int p = blockIdx.x;
    int s = src[p];
    const float* row = (s >= 0) ? (summaries + (size_t)s * D) : (pool + (size_t)p * D);
    float* o = outPool + (size_t)p * D;
    if ((D & 3) == 0) {
        for (int k = (threadIdx.x << 2); k < D; k += (blockDim.x << 2)) {
            float4 v = *(const float4*)(row + k);
            *(float4*)(o + k) = v;
        }
    } else {
        for (int k = threadIdx.x; k < D; k += blockDim.x) o[k] = row[k];
    }
}

extern "C" void kernel_launch(void* const* d_in, const int* in_sizes, int n_in,
                              void* d_out, int out_size, void* d_ws, size_t ws_size,
                              hipStream_t stream) {
    const float* summaries  = (const float*)d_in[0];
    const float* scores     = (const float*)d_in[1];
    const float* pool       = (const float*)d_in[2];
    const float* priorities = (const float*)d_in[3];
    const int*   count      = (const int*)d_in[4];

    int N = in_sizes[1];            // 16384
    int P = in_sizes[3];            // 4096
    int D = in_sizes[0] / N;        // 1024

    float* outPool  = (float*)d_out;
    float* outPrior = outPool + (size_t)P * D;
    float* outCnt   = outPrior + P;
    int*   srcWs    = (int*)d_ws;   // P ints; must survive into gather

    // scratch lives inside outPool: gather fully overwrites it at the end
    float* cval     = outPool;
    int*   csrc     = (int*)outPool + 1 * N;
    float* cvalS    = outPool + 3 * N;
    float* wval     = outPool + 4 * N;
    int*   wsrc     = (int*)outPool + 5 * N;
    int*   writeNum = (int*)outPool + 6 * N;
    float* evV      = outPool + 7 * N;                 // N + 64
    int*   evId     = (int*)outPool + 8 * N + 64;      // N + 64
    int*   Sgbuf    = (int*)outPool + 9 * N + 128;     // N
    int*   survW    = (int*)outPool + 10 * N + 128;    // N
    int*   meta     = (int*)outPool + 11 * N + 128;    // 8
    int*   cnt2     = (int*)outPool + 11 * N + 192;    // N
    int*   cnt4     = (int*)outPool + 12 * N + 192;    // P + N

    const int nb2 = (N + 255) / 256;
    const int nb4 = (P + N + 255) / 256;
    const int ty  = (P + N + K2T - 1) / K2T;           // K2T == K4T == 512

    dim3 g2(nb2, ty), g4(nb4, ty);

    hipMemsetAsync(cnt2, 0, (size_t)N * sizeof(int), stream);
    hipMemsetAsync(cnt4, 0, (size_t)(P + N) * sizeof(int), stream);

    k1_scan<<<1, 1024, 0, stream>>>(scores, priorities, count, N, P,
                                    outPrior, outCnt, srcWs, cval, csrc, meta);
    k2_count<<<g2, 256, 0, stream>>>(outPrior, cval, meta, cnt2);
    k3_compact<<<1, 1024, 0, stream>>>(cval, csrc, cnt2, meta, cvalS, wval, wsrc, writeNum);
    k4_count<<<g4, 256, 0, stream>>>(outPrior, cvalS, meta, P, cnt4);
    k4_scatter<<<nb4, 256, 0, stream>>>(outPrior, cvalS, writeNum, meta, P, cnt4,
                                        evV, evId, survW);
    k5_chain<<<1, 1024, 0, stream>>>(evV, evId, meta, P, Sgbuf, survW);
    k5b_apply<<<nb2, 256, 0, stream>>>(Sgbuf, survW, wval, wsrc, meta, outPrior, srcWs);
    gather_kernel<<<P, 256, 0, stream>>>(summaries, pool, srcWs, outPool, D);
}